// Round 1
// baseline (24.922 us; speedup 1.0000x reference)
//
#include <hip/hip_runtime.h>
#include <math.h>

#define NPTS   543
#define NPER   (NPTS*3)      // 1629 floats per frame
#define MAXL   256
#define NFEAT  1230
#define RED_BLOCKS 64

__constant__ int c_LIP[40] = {61, 146, 91, 181, 84, 17, 314, 405, 321, 375,
                              291, 78, 95, 88, 178, 87, 14, 317, 402, 318,
                              324, 308, 191, 80, 81, 82, 13, 312, 311, 310,
                              415, 185, 40, 39, 37, 0, 267, 269, 270, 409};
__constant__ int c_SPOSE[8] = {500, 502, 504, 501, 503, 505, 512, 513};

__device__ __forceinline__ bool not_nan(float f) { return f == f; }

// Stage 1: per-block partial (sum, sumsq, count) over all input elements, NaN-skipping.
__global__ void reduce1(const float* __restrict__ x, int n, double* __restrict__ part) {
    __shared__ double s_sum[256], s_sq[256], s_cnt[256];
    const int tid = threadIdx.x;
    const long long gtid   = (long long)blockIdx.x * blockDim.x + tid;
    const long long stride = (long long)gridDim.x * blockDim.x;

    double sum = 0.0, sq = 0.0, cnt = 0.0;
    const int n4 = n >> 2;
    const float4* x4 = (const float4*)x;
    for (long long i = gtid; i < n4; i += stride) {
        float4 v = x4[i];
        float a[4] = {v.x, v.y, v.z, v.w};
        #pragma unroll
        for (int k = 0; k < 4; ++k) {
            float f = a[k];
            if (not_nan(f)) { sum += f; sq += (double)f * f; cnt += 1.0; }
        }
    }
    // scalar tail (n % 4 elements)
    const int tail0 = n4 << 2;
    if (gtid < (n - tail0)) {
        float f = x[tail0 + gtid];
        if (not_nan(f)) { sum += f; sq += (double)f * f; cnt += 1.0; }
    }

    s_sum[tid] = sum; s_sq[tid] = sq; s_cnt[tid] = cnt;
    __syncthreads();
    for (int off = 128; off > 0; off >>= 1) {
        if (tid < off) {
            s_sum[tid] += s_sum[tid + off];
            s_sq[tid]  += s_sq[tid + off];
            s_cnt[tid] += s_cnt[tid + off];
        }
        __syncthreads();
    }
    if (tid == 0) {
        part[blockIdx.x * 3 + 0] = s_sum[0];
        part[blockIdx.x * 3 + 1] = s_sq[0];
        part[blockIdx.x * 3 + 2] = s_cnt[0];
    }
}

// Stage 2: finalize mean and 1/std (ddof=1).
__global__ void reduce2(const double* __restrict__ part, int nb, float* __restrict__ stats) {
    if (threadIdx.x == 0 && blockIdx.x == 0) {
        double sum = 0.0, sq = 0.0, cnt = 0.0;
        for (int i = 0; i < nb; ++i) {
            sum += part[i * 3 + 0];
            sq  += part[i * 3 + 1];
            cnt += part[i * 3 + 2];
        }
        double m   = sum / cnt;
        double var = (sq - sum * sum / cnt) / (cnt - 1.0);
        stats[0] = (float)m;
        stats[1] = (float)(1.0 / sqrt(var));
    }
}

// Stage 3: one frame per block. Stage normalized 90-point sets of frames
// (t-1, t, t+1) in LDS, then write the 1230 features for frame t.
__global__ void feat(const float* __restrict__ xyz, const float* __restrict__ stats,
                     float* __restrict__ out, int i0, int L) {
    __shared__ float p_cur[270], p_prev[270], p_next[270];
    const int t   = blockIdx.x;
    const int tid = threadIdx.x;
    const float m     = stats[0];
    const float inv_s = stats[1];
    const bool has_prev = (t > 0);
    const bool has_next = (t < L - 1);

    for (int idx = tid; idx < 270; idx += blockDim.x) {
        const int p = idx / 3, c = idx % 3;
        // landmark index: lhand 468+p | rhand 522+(p-21)=501+p | LIP | SPOSE
        const int lm = (p < 21) ? (468 + p)
                     : (p < 42) ? (501 + p)
                     : (p < 82) ? c_LIP[p - 42]
                                : c_SPOSE[p - 82];
        const long long off = (long long)lm * 3 + c;
        p_cur[idx] = (xyz[(long long)(i0 + t) * NPER + off] - m) * inv_s;
        p_prev[idx] = has_prev ? (xyz[(long long)(i0 + t - 1) * NPER + off] - m) * inv_s : 0.0f;
        p_next[idx] = has_next ? (xyz[(long long)(i0 + t + 1) * NPER + off] - m) * inv_s : 0.0f;
    }
    __syncthreads();

    float* orow = out + (long long)t * NFEAT;
    for (int col = tid; col < NFEAT; col += blockDim.x) {
        float v;
        if (col < 270) {
            v = p_cur[col];
        } else if (col < 540) {               // dfxyz[t] = pts[t] - pts[t+1], 0 at t=L-1
            const int idx = col - 270;
            v = has_next ? (p_cur[idx] - p_next[idx]) : 0.0f;
        } else if (col < 810) {               // dbxyz[t] = pts[t] - pts[t-1], 0 at t=0
            const int idx = col - 540;
            v = has_prev ? (p_cur[idx] - p_prev[idx]) : 0.0f;
        } else {                              // ld (210) then rd (210)
            int k = col - 810;
            int base = 0;
            if (k >= 210) { k -= 210; base = 21; }
            // strict upper-triangle (i<j) of 21 in row-major order
            int i = 0, rem = k, row = 20;
            while (rem >= row) { rem -= row; --row; ++i; }
            const int j = i + 1 + rem;
            const float dx = p_cur[(base + i) * 3 + 0] - p_cur[(base + j) * 3 + 0];
            const float dy = p_cur[(base + i) * 3 + 1] - p_cur[(base + j) * 3 + 1];
            v = sqrtf(dx * dx + dy * dy);
        }
        orow[col] = not_nan(v) ? v : 0.0f;    // final NaN -> 0
    }
}

extern "C" void kernel_launch(void* const* d_in, const int* in_sizes, int n_in,
                              void* d_out, int out_size, void* d_ws, size_t ws_size,
                              hipStream_t stream) {
    const float* xyz = (const float*)d_in[0];
    float* out = (float*)d_out;
    const int n    = in_sizes[0];
    const int L_in = n / NPER;
    const int i0   = (L_in > MAXL) ? (L_in - MAXL) / 2 : 0;
    const int L    = (L_in > MAXL) ? MAXL : L_in;

    double* part = (double*)d_ws;
    float*  stats = (float*)((char*)d_ws + RED_BLOCKS * 3 * sizeof(double));

    reduce1<<<RED_BLOCKS, 256, 0, stream>>>(xyz, n, part);
    reduce2<<<1, 64, 0, stream>>>(part, RED_BLOCKS, stats);
    feat<<<L, 256, 0, stream>>>(xyz, stats, out, i0, L);
}

// Round 2
// 15.625 us; speedup vs baseline: 1.5950x; 1.5950x over previous
//
#include <hip/hip_runtime.h>
#include <math.h>

#define NPTS   543
#define NPER   (NPTS*3)      // 1629 floats per frame
#define MAXL   256
#define NFEAT  1230
#define RED_BLOCKS 64

__constant__ int c_LIP[40] = {61, 146, 91, 181, 84, 17, 314, 405, 321, 375,
                              291, 78, 95, 88, 178, 87, 14, 317, 402, 318,
                              324, 308, 191, 80, 81, 82, 13, 312, 311, 310,
                              415, 185, 40, 39, 37, 0, 267, 269, 270, 409};
__constant__ int c_SPOSE[8] = {500, 502, 504, 501, 503, 505, 512, 513};

__device__ __forceinline__ bool not_nan(float f) { return f == f; }

// Stage 1: per-block partial (sum, sumsq, count), NaN-skipping, fp64 accum.
__global__ void reduce1(const float* __restrict__ x, int n, double* __restrict__ part) {
    __shared__ double s_sum[256], s_sq[256], s_cnt[256];
    const int tid = threadIdx.x;
    const long long gtid   = (long long)blockIdx.x * blockDim.x + tid;
    const long long stride = (long long)gridDim.x * blockDim.x;

    double sum = 0.0, sq = 0.0, cnt = 0.0;
    const int n4 = n >> 2;
    const float4* x4 = (const float4*)x;
    for (long long i = gtid; i < n4; i += stride) {
        float4 v = x4[i];
        float a[4] = {v.x, v.y, v.z, v.w};
        #pragma unroll
        for (int k = 0; k < 4; ++k) {
            float f = a[k];
            if (not_nan(f)) { sum += f; sq += (double)f * f; cnt += 1.0; }
        }
    }
    const int tail0 = n4 << 2;
    if (gtid < (n - tail0)) {
        float f = x[tail0 + gtid];
        if (not_nan(f)) { sum += f; sq += (double)f * f; cnt += 1.0; }
    }

    s_sum[tid] = sum; s_sq[tid] = sq; s_cnt[tid] = cnt;
    __syncthreads();
    for (int off = 128; off > 0; off >>= 1) {
        if (tid < off) {
            s_sum[tid] += s_sum[tid + off];
            s_sq[tid]  += s_sq[tid + off];
            s_cnt[tid] += s_cnt[tid + off];
        }
        __syncthreads();
    }
    if (tid == 0) {
        part[blockIdx.x * 3 + 0] = s_sum[0];
        part[blockIdx.x * 3 + 1] = s_sq[0];
        part[blockIdx.x * 3 + 2] = s_cnt[0];
    }
}

// Stage 2 (fused): wave 0 reduces the 64 partials -> (m, 1/s) while waves 1-3
// stage the RAW 90-point sets of frames (t-1, t, t+1); normalization is folded
// into the output pass (diffs/distances only need the 1/s scale).
__global__ void __launch_bounds__(256)
featfused(const float* __restrict__ xyz, const double* __restrict__ part,
          float* __restrict__ out, int i0, int L) {
    __shared__ float p_cur[270], p_prev[270], p_next[270];
    __shared__ float s_m, s_is;
    const int t   = blockIdx.x;
    const int tid = threadIdx.x;
    const bool has_prev = (t > 0);
    const bool has_next = (t < L - 1);

    if (tid < 64) {
        // one wave: butterfly-reduce 64 partial triples
        double sum = part[tid * 3 + 0];
        double sq  = part[tid * 3 + 1];
        double cnt = part[tid * 3 + 2];
        #pragma unroll
        for (int off = 32; off > 0; off >>= 1) {
            sum += __shfl_down(sum, off, 64);
            sq  += __shfl_down(sq,  off, 64);
            cnt += __shfl_down(cnt, off, 64);
        }
        if (tid == 0) {
            double m   = sum / cnt;
            double var = (sq - sum * sum / cnt) / (cnt - 1.0);
            s_m  = (float)m;
            s_is = (float)(1.0 / sqrt(var));
        }
    } else {
        // waves 1-3: gather raw points for cur/prev/next (810 scalar items)
        for (int idx = tid - 64; idx < 810; idx += 192) {
            const int f   = idx / 270;          // 0=cur 1=prev 2=next
            const int e   = idx - f * 270;      // element within frame set
            const int p   = e / 3, c = e - p * 3;
            const int lm = (p < 21) ? (468 + p)
                         : (p < 42) ? (501 + p)
                         : (p < 82) ? c_LIP[p - 42]
                                    : c_SPOSE[p - 82];
            const long long off = (long long)lm * 3 + c;
            if (f == 0) {
                p_cur[e] = xyz[(long long)(i0 + t) * NPER + off];
            } else if (f == 1) {
                p_prev[e] = has_prev ? xyz[(long long)(i0 + t - 1) * NPER + off] : 0.0f;
            } else {
                p_next[e] = has_next ? xyz[(long long)(i0 + t + 1) * NPER + off] : 0.0f;
            }
        }
    }
    __syncthreads();

    const float m     = s_m;
    const float inv_s = s_is;
    float* orow = out + (long long)t * NFEAT;
    for (int col = tid; col < NFEAT; col += 256) {
        float v;
        if (col < 270) {
            v = (p_cur[col] - m) * inv_s;
        } else if (col < 540) {               // dfxyz[t] = pts[t] - pts[t+1], 0 at t=L-1
            const int idx = col - 270;
            v = has_next ? (p_cur[idx] - p_next[idx]) * inv_s : 0.0f;
        } else if (col < 810) {               // dbxyz[t] = pts[t] - pts[t-1], 0 at t=0
            const int idx = col - 540;
            v = has_prev ? (p_cur[idx] - p_prev[idx]) * inv_s : 0.0f;
        } else {                              // ld (210) then rd (210)
            int k = col - 810;
            int base = 0;
            if (k >= 210) { k -= 210; base = 21; }
            // strict upper-triangle (i<j) of 21 in row-major order
            int i = 0, rem = k, row = 20;
            while (rem >= row) { rem -= row; --row; ++i; }
            const int j = i + 1 + rem;
            const float dx = p_cur[(base + i) * 3 + 0] - p_cur[(base + j) * 3 + 0];
            const float dy = p_cur[(base + i) * 3 + 1] - p_cur[(base + j) * 3 + 1];
            v = sqrtf(dx * dx + dy * dy) * inv_s;
        }
        orow[col] = not_nan(v) ? v : 0.0f;    // final NaN -> 0
    }
}

extern "C" void kernel_launch(void* const* d_in, const int* in_sizes, int n_in,
                              void* d_out, int out_size, void* d_ws, size_t ws_size,
                              hipStream_t stream) {
    const float* xyz = (const float*)d_in[0];
    float* out = (float*)d_out;
    const int n    = in_sizes[0];
    const int L_in = n / NPER;
    const int i0   = (L_in > MAXL) ? (L_in - MAXL) / 2 : 0;
    const int L    = (L_in > MAXL) ? MAXL : L_in;

    double* part = (double*)d_ws;

    reduce1<<<RED_BLOCKS, 256, 0, stream>>>(xyz, n, part);
    featfused<<<L, 256, 0, stream>>>(xyz, part, out, i0, L);
}